// Round 1
// baseline (512.892 us; speedup 1.0000x reference)
//
#include <hip/hip_runtime.h>
#include <math.h>

#define NB     32
#define FH     11
#define FW     20
#define CIN    512
#define CMID   1024
#define NANG   17
#define NPREDD 77
#define NEDGE  42
#define NPROPP 714
#define NOFF   72
#define NCLS   34
#define NREGR  1241
#define N2PAD  1280
#define MTOT   1344      // NB * NEDGE
#define NSTRIPSF 71.0f

// ---------------- gather edge pixels: A0[m][c], m = b*42+e ----------------
__global__ __launch_bounds__(256) void k_gather(const float* __restrict__ feat,
                                                float* __restrict__ A0)
{
    int idx = blockIdx.x * 256 + threadIdx.x;    // exactly MTOT*CIN = 688128
    int m = idx >> 9, c = idx & 511;
    int b = m / NEDGE, e = m - b * NEDGE;
    int h, w;
    if (e < FH)          { h = e;      w = 0;      }
    else if (e < 2 * FH) { h = e - FH; w = FW - 1; }
    else                 { h = FH - 1; w = e - 2 * FH; }
    A0[idx] = feat[((size_t)(b * CIN + c) * FH + h) * FW + w];
}

// ---------------- GEMM1: C1[1344][1024] = A0[1344][512] * Wconv[1024][512]^T + b ----
__global__ __launch_bounds__(256) void k_gemm1(const float* __restrict__ A,
                                               const float* __restrict__ W,
                                               const float* __restrict__ bias,
                                               float* __restrict__ C)
{
    __shared__ __align__(16) float As[16][68];
    __shared__ __align__(16) float Bs[16][68];
    const int K = CIN;
    int tid = threadIdx.x;
    int m0 = blockIdx.y * 64, n0 = blockIdx.x * 64;
    int tn = tid & 15, tm = tid >> 4;
    int lr = tid >> 2, lc = (tid & 3) << 2;
    const float* Ap = A + (size_t)(m0 + lr) * K + lc;
    const float* Wp = W + (size_t)(n0 + lr) * K + lc;
    float acc[4][4];
#pragma unroll
    for (int i = 0; i < 4; ++i)
#pragma unroll
        for (int j = 0; j < 4; ++j) acc[i][j] = 0.f;

    for (int k0 = 0; k0 < K; k0 += 16) {
        float4 av = *(const float4*)(Ap + k0);
        float4 wv = *(const float4*)(Wp + k0);
        As[lc + 0][lr] = av.x; As[lc + 1][lr] = av.y; As[lc + 2][lr] = av.z; As[lc + 3][lr] = av.w;
        Bs[lc + 0][lr] = wv.x; Bs[lc + 1][lr] = wv.y; Bs[lc + 2][lr] = wv.z; Bs[lc + 3][lr] = wv.w;
        __syncthreads();
#pragma unroll
        for (int kk = 0; kk < 16; ++kk) {
            float4 a = *(const float4*)&As[kk][tm << 2];
            float4 b = *(const float4*)&Bs[kk][tn << 2];
            float ar[4] = {a.x, a.y, a.z, a.w};
            float br[4] = {b.x, b.y, b.z, b.w};
#pragma unroll
            for (int i = 0; i < 4; ++i)
#pragma unroll
                for (int j = 0; j < 4; ++j)
                    acc[i][j] = fmaf(ar[i], br[j], acc[i][j]);
        }
        __syncthreads();
    }
    float bb[4];
#pragma unroll
    for (int j = 0; j < 4; ++j) bb[j] = bias[n0 + (tn << 2) + j];
#pragma unroll
    for (int i = 0; i < 4; ++i) {
        float4 o;
        o.x = acc[i][0] + bb[0];
        o.y = acc[i][1] + bb[1];
        o.z = acc[i][2] + bb[2];
        o.w = acc[i][3] + bb[3];
        *(float4*)(C + (size_t)(m0 + (tm << 2) + i) * CMID + n0 + (tn << 2)) = o;
    }
}

// ---------------- GEMM2: C2[1344][1280] = C1 * [Wcls;Wreg;0]^T + [bcls;breg;0] ----
__global__ __launch_bounds__(256) void k_gemm2(const float* __restrict__ A,
                                               const float* __restrict__ Wcls,
                                               const float* __restrict__ bcls,
                                               const float* __restrict__ Wreg,
                                               const float* __restrict__ breg,
                                               float* __restrict__ C)
{
    __shared__ __align__(16) float As[16][68];
    __shared__ __align__(16) float Bs[16][68];
    const int K = CMID;
    int tid = threadIdx.x;
    int m0 = blockIdx.y * 64, n0 = blockIdx.x * 64;
    int tn = tid & 15, tm = tid >> 4;
    int lr = tid >> 2, lc = (tid & 3) << 2;
    int nrow = n0 + lr;
    const float* Wp = Wcls;
    bool wvalid = true;
    if (nrow < NCLS)              Wp = Wcls + (size_t)nrow * K + lc;
    else if (nrow < NCLS + NREGR) Wp = Wreg + (size_t)(nrow - NCLS) * K + lc;
    else                          wvalid = false;
    const float* Ap = A + (size_t)(m0 + lr) * K + lc;
    float acc[4][4];
#pragma unroll
    for (int i = 0; i < 4; ++i)
#pragma unroll
        for (int j = 0; j < 4; ++j) acc[i][j] = 0.f;

    for (int k0 = 0; k0 < K; k0 += 16) {
        float4 av = *(const float4*)(Ap + k0);
        float4 wv = wvalid ? *(const float4*)(Wp + k0) : make_float4(0.f, 0.f, 0.f, 0.f);
        As[lc + 0][lr] = av.x; As[lc + 1][lr] = av.y; As[lc + 2][lr] = av.z; As[lc + 3][lr] = av.w;
        Bs[lc + 0][lr] = wv.x; Bs[lc + 1][lr] = wv.y; Bs[lc + 2][lr] = wv.z; Bs[lc + 3][lr] = wv.w;
        __syncthreads();
#pragma unroll
        for (int kk = 0; kk < 16; ++kk) {
            float4 a = *(const float4*)&As[kk][tm << 2];
            float4 b = *(const float4*)&Bs[kk][tn << 2];
            float ar[4] = {a.x, a.y, a.z, a.w};
            float br[4] = {b.x, b.y, b.z, b.w};
#pragma unroll
            for (int i = 0; i < 4; ++i)
#pragma unroll
                for (int j = 0; j < 4; ++j)
                    acc[i][j] = fmaf(ar[i], br[j], acc[i][j]);
        }
        __syncthreads();
    }
    float bb[4];
#pragma unroll
    for (int j = 0; j < 4; ++j) {
        int n = n0 + (tn << 2) + j;
        bb[j] = (n < NCLS) ? bcls[n] : ((n < NCLS + NREGR) ? breg[n - NCLS] : 0.f);
    }
#pragma unroll
    for (int i = 0; i < 4; ++i) {
        float4 o;
        o.x = acc[i][0] + bb[0];
        o.y = acc[i][1] + bb[1];
        o.z = acc[i][2] + bb[2];
        o.w = acc[i][3] + bb[3];
        *(float4*)(C + (size_t)(m0 + (tm << 2) + i) * N2PAD + n0 + (tn << 2)) = o;
    }
}

// ---------------- assemble proposals + scores + start/end ----------------
__global__ __launch_bounds__(256) void k_assemble(const float* __restrict__ C2,
                                                  const float* __restrict__ AD,
                                                  float* __restrict__ outP,
                                                  float* __restrict__ outS,
                                                  float* __restrict__ startv,
                                                  float* __restrict__ endv)
{
    int mb = blockIdx.x;                 // 0..1343
    int b = mb / NEDGE, e = mb - b * NEDGE;
    const float* c2 = C2 + (size_t)mb * N2PAD;
    int tid = threadIdx.x;
    for (int idx = tid; idx < NANG * NPREDD; idx += 256) {
        int a = idx / NPREDD, p = idx - a * NPREDD;
        int prop = e * NANG + a;
        float v;
        if (p < 2) v = c2[a * 2 + p];
        else {
            v = AD[prop * NPREDD + p];
            if (p >= 4) v += c2[NCLS + a * 73 + (p - 4)];
        }
        outP[((size_t)b * NPROPP + prop) * NPREDD + p] = v;
    }
    if (tid < NANG) {
        int a = tid, prop = e * NANG + a;
        float c0 = c2[2 * a], c1 = c2[2 * a + 1];
        float mx = fmaxf(c0, c1);
        float e0 = expf(c0 - mx), e1 = expf(c1 - mx);
        outS[b * NPROPP + prop] = e1 / (e0 + e1);
        float p2 = AD[prop * NPREDD + 2];
        float p4 = AD[prop * NPREDD + 4] + c2[NCLS + a * 73];
        float st = fminf(fmaxf(rintf(p2 * NSTRIPSF), 0.0f), NSTRIPSF);  // round half-to-even
        float en = fminf(fmaxf(st + p4 - 1.0f, 0.0f), NSTRIPSF);
        startv[b * 720 + prop] = st;
        endv[b * 720 + prop] = en;
    }
}

// ---------------- per-batch stable descending rank sort ----------------
__global__ __launch_bounds__(256) void k_sort(const float* __restrict__ scores,
                                              int* __restrict__ order)
{
    int b = blockIdx.x, tid = threadIdx.x;
    __shared__ float s[NPROPP];
    for (int i = tid; i < NPROPP; i += 256) s[i] = scores[b * NPROPP + i];
    __syncthreads();
    for (int i = tid; i < NPROPP; i += 256) {
        float si = s[i];
        int r = 0;
        for (int j = 0; j < NPROPP; ++j) {
            float sj = s[j];
            r += (sj > si) || (sj == si && j < i);
        }
        order[b * 720 + r] = i;
    }
}

// ---------------- suppression matrix in sorted order, bit-packed ----------------
#define SUP_IT 32
#define SUP_JT 64
__global__ __launch_bounds__(256) void k_supmat(const float* __restrict__ outP,
                                                const float* __restrict__ startv,
                                                const float* __restrict__ endv,
                                                const int* __restrict__ order,
                                                unsigned long long* __restrict__ sup)
{
    int jt = blockIdx.x, it = blockIdx.y, b = blockIdx.z;
    int i0 = it * SUP_IT, j0 = jt * SUP_JT;
    if (j0 + SUP_JT - 1 < i0) return;   // only j>i bits are ever read (masked in scan)
    __shared__ float XI[SUP_IT][73];
    __shared__ float XJ[SUP_JT][73];
    __shared__ float SI[SUP_IT], EI[SUP_IT], SJ[SUP_JT], EJ[SUP_JT];
    __shared__ int   OIJ[SUP_IT + SUP_JT];
    int tid = threadIdx.x;
    if (tid < SUP_IT + SUP_JT) {
        int pos = (tid < SUP_IT) ? (i0 + tid) : (j0 + (tid - SUP_IT));
        int o = (pos < NPROPP) ? order[b * 720 + pos] : -1;
        OIJ[tid] = o;
        float st = (o >= 0) ? startv[b * 720 + o] : 0.f;
        float en = (o >= 0) ? endv[b * 720 + o] : -2.f;
        if (tid < SUP_IT) { SI[tid] = st; EI[tid] = en; }
        else              { SJ[tid - SUP_IT] = st; EJ[tid - SUP_IT] = en; }
    }
    __syncthreads();
    for (int x = tid; x < (SUP_IT + SUP_JT) * NOFF; x += 256) {
        int r = x / NOFF, k = x - r * NOFF;
        int o = OIJ[r];
        float v = (o >= 0) ? outP[((size_t)b * NPROPP + o) * NPREDD + 5 + k] : 0.f;
        if (r < SUP_IT) XI[r][k] = v; else XJ[r - SUP_IT][k] = v;
    }
    __syncthreads();
    int lane = tid & 63, wv = tid >> 6;
    int j = j0 + lane;
    float sj = SJ[lane], ej = EJ[lane];
    const float* xj = &XJ[lane][0];
#pragma unroll 1
    for (int rep = 0; rep < 8; ++rep) {
        int iloc = wv * 8 + rep;
        int il = i0 + iloc;
        float si = SI[iloc], ei = EI[iloc];
        float s = fmaxf(si, sj), e = fminf(ei, ej);
        float cnt = e - s + 1.0f;
        const float* xi = &XI[iloc][0];
        float sum = 0.f;
#pragma unroll
        for (int k = 0; k < NOFF; ++k) {
            float d = xi[k] - xj[k];
            bool in = ((float)k >= s) && ((float)k <= e);
            sum += in ? fabsf(d) : 0.f;
        }
        bool sp = false;
        if (cnt > 0.f) sp = (sum / fmaxf(cnt, 1.0f)) < 15.0f;
        bool valid = (il < NPROPP) && (j < NPROPP);
        unsigned long long msk = __ballot(valid && sp);
        if (lane == 0 && il < NPROPP)
            sup[((size_t)b * NPROPP + il) * 12 + jt] = msk;
    }
}

// ---------------- sequential NMS scan (per batch, 1 wave) ----------------
__global__ __launch_bounds__(64) void k_scan(const unsigned long long* __restrict__ sup,
                                             const int* __restrict__ order,
                                             float* __restrict__ keep_out)
{
    int b = blockIdx.x, lane = threadIdx.x;
    __shared__ float keepv[NPROPP];
    __shared__ int ord[NPROPP];
    for (int x = lane; x < NPROPP; x += 64) { keepv[x] = 0.f; ord[x] = order[b * 720 + x]; }
    __syncthreads();
    unsigned long long srow[12];
    unsigned long long supp[12];
#pragma unroll
    for (int w = 0; w < 12; ++w) supp[w] = 0ull;
    const unsigned long long* base = sup + (size_t)b * NPROPP * 12;
    for (int i = 0; i < NPROPP; ++i) {
        if ((i & 63) == 0) {
            int r = i + lane;   // lane l caches sorted row i+l for this 64-chunk
#pragma unroll
            for (int w = 0; w < 12; ++w)
                srow[w] = (r < NPROPP) ? base[(size_t)r * 12 + w] : 0ull;
        }
        int iw = i >> 6, ib = i & 63;
        bool keep = ((supp[iw] >> ib) & 1ull) == 0ull;   // uniform across lanes
        if (keep) {
#pragma unroll
            for (int w = 0; w < 12; ++w) {
                unsigned long long rv = __shfl(srow[w], ib);   // broadcast row i
                unsigned long long m = (w > iw) ? ~0ull
                                   : ((w == iw) ? ((ib == 63) ? 0ull : (~0ull << (ib + 1))) : 0ull);
                supp[w] |= rv & m;   // poisoned never-written words always masked to 0
            }
            if (lane == 0) keepv[ord[i]] = 1.f;
        }
    }
    __syncthreads();
    for (int x = lane; x < NPROPP; x += 64) keep_out[b * NPROPP + x] = keepv[x];
}

extern "C" void kernel_launch(void* const* d_in, const int* in_sizes, int n_in,
                              void* d_out, int out_size, void* d_ws, size_t ws_size,
                              hipStream_t stream)
{
    const float* feat  = (const float*)d_in[0];
    const float* Wconv = (const float*)d_in[1];
    const float* bconv = (const float*)d_in[2];
    const float* Wcls  = (const float*)d_in[3];
    const float* bcls  = (const float*)d_in[4];
    const float* Wreg  = (const float*)d_in[5];
    const float* breg  = (const float*)d_in[6];
    const float* AD    = (const float*)d_in[8];   // anchors_anchor_dim (714,77)

    float* out  = (float*)d_out;
    float* outP = out;                                     // proposals 32*714*77
    float* outK = out + (size_t)NB * NPROPP * NPREDD;      // keep mask  32*714
    float* outS = outK + (size_t)NB * NPROPP;              // scores     32*714

    float* ws = (float*)d_ws;
    float* A0 = ws;                   // [0, 688128)         dead after gemm1
    float* C1 = ws + 688128;          // [688128, 2064384)   dead after gemm2
    float* C2 = ws + 2064384;         // [2064384, 3784704)
    // reuse A0 region (dead by the time these are written):
    float* startv = ws;                                    // 32*720 floats
    float* endv   = ws + 23040;                            // 32*720 floats
    int*   order  = (int*)(ws + 46080);                    // 32*720 ints
    unsigned long long* sup = (unsigned long long*)(ws + 69120);  // 32*714*12 u64 = 2.09 MiB

    k_gather  <<<dim3(2688),        dim3(256), 0, stream>>>(feat, A0);
    k_gemm1   <<<dim3(16, 21),      dim3(256), 0, stream>>>(A0, Wconv, bconv, C1);
    k_gemm2   <<<dim3(20, 21),      dim3(256), 0, stream>>>(C1, Wcls, bcls, Wreg, breg, C2);
    k_assemble<<<dim3(MTOT),        dim3(256), 0, stream>>>(C2, AD, outP, outS, startv, endv);
    k_sort    <<<dim3(NB),          dim3(256), 0, stream>>>(outS, order);
    k_supmat  <<<dim3(12, 23, NB),  dim3(256), 0, stream>>>(outP, startv, endv, order, sup);
    k_scan    <<<dim3(NB),          dim3(64),  0, stream>>>(sup, order, outK);
}

// Round 2
// 429.398 us; speedup vs baseline: 1.1944x; 1.1944x over previous
//
#include <hip/hip_runtime.h>
#include <math.h>

#define NB     32
#define FH     11
#define FW     20
#define CIN    512
#define CMID   1024
#define NANG   17
#define NPREDD 77
#define NEDGE  42
#define NPROPP 714
#define NOFF   72
#define NCLS   34
#define NREGR  1241
#define N2PAD  1280
#define MTOT   1344      // NB * NEDGE
#define NSTRIPSF 71.0f

// ---------------- gather edge pixels: A0[m][c], m = b*42+e ----------------
__global__ __launch_bounds__(256) void k_gather(const float* __restrict__ feat,
                                                float* __restrict__ A0)
{
    int idx = blockIdx.x * 256 + threadIdx.x;    // exactly MTOT*CIN = 688128
    int m = idx >> 9, c = idx & 511;
    int b = m / NEDGE, e = m - b * NEDGE;
    int h, w;
    if (e < FH)          { h = e;      w = 0;      }
    else if (e < 2 * FH) { h = e - FH; w = FW - 1; }
    else                 { h = FH - 1; w = e - 2 * FH; }
    A0[idx] = feat[((size_t)(b * CIN + c) * FH + h) * FW + w];
}

// ---------------- GEMM1: C1[1344][1024] = A0[1344][512] * Wconv[1024][512]^T + b ----
__global__ __launch_bounds__(256) void k_gemm1(const float* __restrict__ A,
                                               const float* __restrict__ W,
                                               const float* __restrict__ bias,
                                               float* __restrict__ C)
{
    __shared__ __align__(16) float As[16][68];
    __shared__ __align__(16) float Bs[16][68];
    const int K = CIN;
    int tid = threadIdx.x;
    int m0 = blockIdx.y * 64, n0 = blockIdx.x * 64;
    int tn = tid & 15, tm = tid >> 4;
    int lr = tid >> 2, lc = (tid & 3) << 2;
    const float* Ap = A + (size_t)(m0 + lr) * K + lc;
    const float* Wp = W + (size_t)(n0 + lr) * K + lc;
    float acc[4][4];
#pragma unroll
    for (int i = 0; i < 4; ++i)
#pragma unroll
        for (int j = 0; j < 4; ++j) acc[i][j] = 0.f;

    for (int k0 = 0; k0 < K; k0 += 16) {
        float4 av = *(const float4*)(Ap + k0);
        float4 wv = *(const float4*)(Wp + k0);
        As[lc + 0][lr] = av.x; As[lc + 1][lr] = av.y; As[lc + 2][lr] = av.z; As[lc + 3][lr] = av.w;
        Bs[lc + 0][lr] = wv.x; Bs[lc + 1][lr] = wv.y; Bs[lc + 2][lr] = wv.z; Bs[lc + 3][lr] = wv.w;
        __syncthreads();
#pragma unroll
        for (int kk = 0; kk < 16; ++kk) {
            float4 a = *(const float4*)&As[kk][tm << 2];
            float4 b = *(const float4*)&Bs[kk][tn << 2];
            float ar[4] = {a.x, a.y, a.z, a.w};
            float br[4] = {b.x, b.y, b.z, b.w};
#pragma unroll
            for (int i = 0; i < 4; ++i)
#pragma unroll
                for (int j = 0; j < 4; ++j)
                    acc[i][j] = fmaf(ar[i], br[j], acc[i][j]);
        }
        __syncthreads();
    }
    float bb[4];
#pragma unroll
    for (int j = 0; j < 4; ++j) bb[j] = bias[n0 + (tn << 2) + j];
#pragma unroll
    for (int i = 0; i < 4; ++i) {
        float4 o;
        o.x = acc[i][0] + bb[0];
        o.y = acc[i][1] + bb[1];
        o.z = acc[i][2] + bb[2];
        o.w = acc[i][3] + bb[3];
        *(float4*)(C + (size_t)(m0 + (tm << 2) + i) * CMID + n0 + (tn << 2)) = o;
    }
}

// ---------------- GEMM2: C2[1344][1280] = C1 * [Wcls;Wreg;0]^T + [bcls;breg;0] ----
__global__ __launch_bounds__(256) void k_gemm2(const float* __restrict__ A,
                                               const float* __restrict__ Wcls,
                                               const float* __restrict__ bcls,
                                               const float* __restrict__ Wreg,
                                               const float* __restrict__ breg,
                                               float* __restrict__ C)
{
    __shared__ __align__(16) float As[16][68];
    __shared__ __align__(16) float Bs[16][68];
    const int K = CMID;
    int tid = threadIdx.x;
    int m0 = blockIdx.y * 64, n0 = blockIdx.x * 64;
    int tn = tid & 15, tm = tid >> 4;
    int lr = tid >> 2, lc = (tid & 3) << 2;
    int nrow = n0 + lr;
    const float* Wp = Wcls;
    bool wvalid = true;
    if (nrow < NCLS)              Wp = Wcls + (size_t)nrow * K + lc;
    else if (nrow < NCLS + NREGR) Wp = Wreg + (size_t)(nrow - NCLS) * K + lc;
    else                          wvalid = false;
    const float* Ap = A + (size_t)(m0 + lr) * K + lc;
    float acc[4][4];
#pragma unroll
    for (int i = 0; i < 4; ++i)
#pragma unroll
        for (int j = 0; j < 4; ++j) acc[i][j] = 0.f;

    for (int k0 = 0; k0 < K; k0 += 16) {
        float4 av = *(const float4*)(Ap + k0);
        float4 wv = wvalid ? *(const float4*)(Wp + k0) : make_float4(0.f, 0.f, 0.f, 0.f);
        As[lc + 0][lr] = av.x; As[lc + 1][lr] = av.y; As[lc + 2][lr] = av.z; As[lc + 3][lr] = av.w;
        Bs[lc + 0][lr] = wv.x; Bs[lc + 1][lr] = wv.y; Bs[lc + 2][lr] = wv.z; Bs[lc + 3][lr] = wv.w;
        __syncthreads();
#pragma unroll
        for (int kk = 0; kk < 16; ++kk) {
            float4 a = *(const float4*)&As[kk][tm << 2];
            float4 b = *(const float4*)&Bs[kk][tn << 2];
            float ar[4] = {a.x, a.y, a.z, a.w};
            float br[4] = {b.x, b.y, b.z, b.w};
#pragma unroll
            for (int i = 0; i < 4; ++i)
#pragma unroll
                for (int j = 0; j < 4; ++j)
                    acc[i][j] = fmaf(ar[i], br[j], acc[i][j]);
        }
        __syncthreads();
    }
    float bb[4];
#pragma unroll
    for (int j = 0; j < 4; ++j) {
        int n = n0 + (tn << 2) + j;
        bb[j] = (n < NCLS) ? bcls[n] : ((n < NCLS + NREGR) ? breg[n - NCLS] : 0.f);
    }
#pragma unroll
    for (int i = 0; i < 4; ++i) {
        float4 o;
        o.x = acc[i][0] + bb[0];
        o.y = acc[i][1] + bb[1];
        o.z = acc[i][2] + bb[2];
        o.w = acc[i][3] + bb[3];
        *(float4*)(C + (size_t)(m0 + (tm << 2) + i) * N2PAD + n0 + (tn << 2)) = o;
    }
}

// ---------------- assemble proposals + scores + start/end ----------------
__global__ __launch_bounds__(256) void k_assemble(const float* __restrict__ C2,
                                                  const float* __restrict__ AD,
                                                  float* __restrict__ outP,
                                                  float* __restrict__ outS,
                                                  float* __restrict__ startv,
                                                  float* __restrict__ endv)
{
    int mb = blockIdx.x;                 // 0..1343
    int b = mb / NEDGE, e = mb - b * NEDGE;
    const float* c2 = C2 + (size_t)mb * N2PAD;
    int tid = threadIdx.x;
    for (int idx = tid; idx < NANG * NPREDD; idx += 256) {
        int a = idx / NPREDD, p = idx - a * NPREDD;
        int prop = e * NANG + a;
        float v;
        if (p < 2) v = c2[a * 2 + p];
        else {
            v = AD[prop * NPREDD + p];
            if (p >= 4) v += c2[NCLS + a * 73 + (p - 4)];
        }
        outP[((size_t)b * NPROPP + prop) * NPREDD + p] = v;
    }
    if (tid < NANG) {
        int a = tid, prop = e * NANG + a;
        float c0 = c2[2 * a], c1 = c2[2 * a + 1];
        float mx = fmaxf(c0, c1);
        float e0 = expf(c0 - mx), e1 = expf(c1 - mx);
        outS[b * NPROPP + prop] = e1 / (e0 + e1);
        float p2 = AD[prop * NPREDD + 2];
        float p4 = AD[prop * NPREDD + 4] + c2[NCLS + a * 73];
        float st = fminf(fmaxf(rintf(p2 * NSTRIPSF), 0.0f), NSTRIPSF);  // round half-to-even
        float en = fminf(fmaxf(st + p4 - 1.0f, 0.0f), NSTRIPSF);
        startv[b * 720 + prop] = st;
        endv[b * 720 + prop] = en;
    }
}

// ---------------- per-batch stable descending rank sort ----------------
__global__ __launch_bounds__(256) void k_sort(const float* __restrict__ scores,
                                              int* __restrict__ order)
{
    int b = blockIdx.x, tid = threadIdx.x;
    __shared__ float s[NPROPP];
    for (int i = tid; i < NPROPP; i += 256) s[i] = scores[b * NPROPP + i];
    __syncthreads();
    for (int i = tid; i < NPROPP; i += 256) {
        float si = s[i];
        int r = 0;
        for (int j = 0; j < NPROPP; ++j) {
            float sj = s[j];
            r += (sj > si) || (sj == si && j < i);
        }
        order[b * 720 + r] = i;
    }
}

// ---------------- suppression matrix in sorted order, bit-packed ----------------
// Key fact: end = clip(start + p4 - 1, 0, 71) with p4 ~ N(0,0.3), so the strip
// intersection [max(si,sj), min(ei,ej)] is almost always empty or 1 element.
// Loop only k = ks..ke (integer bounds) instead of all 72 masked iterations.
// Empty integer range with cnt>0 gives sum=0 -> dist=0 < 15 -> suppress,
// exactly matching the reference's masked-sum semantics.
#define SUP_IT 32
#define SUP_JT 64
__global__ __launch_bounds__(256) void k_supmat(const float* __restrict__ outP,
                                                const float* __restrict__ startv,
                                                const float* __restrict__ endv,
                                                const int* __restrict__ order,
                                                unsigned long long* __restrict__ sup)
{
    int jt = blockIdx.x, it = blockIdx.y, b = blockIdx.z;
    int i0 = it * SUP_IT, j0 = jt * SUP_JT;
    if (j0 + SUP_JT - 1 < i0) return;   // only j>i bits are ever read (masked in scan)
    __shared__ float XI[SUP_IT][73];
    __shared__ float XJ[SUP_JT][73];
    __shared__ float SI[SUP_IT], EI[SUP_IT], SJ[SUP_JT], EJ[SUP_JT];
    __shared__ int   OIJ[SUP_IT + SUP_JT];
    int tid = threadIdx.x;
    if (tid < SUP_IT + SUP_JT) {
        int pos = (tid < SUP_IT) ? (i0 + tid) : (j0 + (tid - SUP_IT));
        int o = (pos < NPROPP) ? order[b * 720 + pos] : -1;
        OIJ[tid] = o;
        float st = (o >= 0) ? startv[b * 720 + o] : 0.f;
        float en = (o >= 0) ? endv[b * 720 + o] : -2.f;   // cnt<=-1 -> never suppress
        if (tid < SUP_IT) { SI[tid] = st; EI[tid] = en; }
        else              { SJ[tid - SUP_IT] = st; EJ[tid - SUP_IT] = en; }
    }
    __syncthreads();
    for (int x = tid; x < (SUP_IT + SUP_JT) * NOFF; x += 256) {
        int r = x / NOFF, k = x - r * NOFF;
        int o = OIJ[r];
        float v = (o >= 0) ? outP[((size_t)b * NPROPP + o) * NPREDD + 5 + k] : 0.f;
        if (r < SUP_IT) XI[r][k] = v; else XJ[r - SUP_IT][k] = v;
    }
    __syncthreads();
    int lane = tid & 63, wv = tid >> 6;
    int j = j0 + lane;
    float sj = SJ[lane], ej = EJ[lane];
#pragma unroll 1
    for (int rep = 0; rep < 8; ++rep) {
        int iloc = wv * 8 + rep;
        int il = i0 + iloc;
        float si = SI[iloc], ei = EI[iloc];
        float s = fmaxf(si, sj), e = fminf(ei, ej);
        float cnt = e - s + 1.0f;
        bool sp = false;
        if (cnt > 0.f) {
            int ks = (int)s;            // s is integer-valued, >= 0
            int ke = (int)e;            // e >= 0 here; trunc == floor
            float sum = 0.f;
            for (int k = ks; k <= ke; ++k)     // typically 0..2 iterations
                sum += fabsf(XI[iloc][k] - XJ[lane][k]);
            sp = (sum / fmaxf(cnt, 1.0f)) < 15.0f;
        }
        bool valid = (il < NPROPP) && (j < NPROPP);
        unsigned long long msk = __ballot(valid && sp);
        if (lane == 0 && il < NPROPP)
            sup[((size_t)b * NPROPP + il) * 12 + jt] = msk;
    }
}

// ---------------- sequential NMS scan (per batch, 1 wave) ----------------
__global__ __launch_bounds__(64) void k_scan(const unsigned long long* __restrict__ sup,
                                             const int* __restrict__ order,
                                             float* __restrict__ keep_out)
{
    int b = blockIdx.x, lane = threadIdx.x;
    __shared__ float keepv[NPROPP];
    __shared__ int ord[NPROPP];
    for (int x = lane; x < NPROPP; x += 64) { keepv[x] = 0.f; ord[x] = order[b * 720 + x]; }
    __syncthreads();
    unsigned long long srow[12];
    unsigned long long supp[12];
#pragma unroll
    for (int w = 0; w < 12; ++w) supp[w] = 0ull;
    const unsigned long long* base = sup + (size_t)b * NPROPP * 12;
    for (int i = 0; i < NPROPP; ++i) {
        if ((i & 63) == 0) {
            int r = i + lane;   // lane l caches sorted row i+l for this 64-chunk
#pragma unroll
            for (int w = 0; w < 12; ++w)
                srow[w] = (r < NPROPP) ? base[(size_t)r * 12 + w] : 0ull;
        }
        int iw = i >> 6, ib = i & 63;
        bool keep = ((supp[iw] >> ib) & 1ull) == 0ull;   // uniform across lanes
        if (keep) {
#pragma unroll
            for (int w = 0; w < 12; ++w) {
                unsigned long long rv = __shfl(srow[w], ib);   // broadcast row i
                unsigned long long m = (w > iw) ? ~0ull
                                   : ((w == iw) ? ((ib == 63) ? 0ull : (~0ull << (ib + 1))) : 0ull);
                supp[w] |= rv & m;   // poisoned never-written words always masked to 0
            }
            if (lane == 0) keepv[ord[i]] = 1.f;
        }
    }
    __syncthreads();
    for (int x = lane; x < NPROPP; x += 64) keep_out[b * NPROPP + x] = keepv[x];
}

extern "C" void kernel_launch(void* const* d_in, const int* in_sizes, int n_in,
                              void* d_out, int out_size, void* d_ws, size_t ws_size,
                              hipStream_t stream)
{
    const float* feat  = (const float*)d_in[0];
    const float* Wconv = (const float*)d_in[1];
    const float* bconv = (const float*)d_in[2];
    const float* Wcls  = (const float*)d_in[3];
    const float* bcls  = (const float*)d_in[4];
    const float* Wreg  = (const float*)d_in[5];
    const float* breg  = (const float*)d_in[6];
    const float* AD    = (const float*)d_in[8];   // anchors_anchor_dim (714,77)

    float* out  = (float*)d_out;
    float* outP = out;                                     // proposals 32*714*77
    float* outK = out + (size_t)NB * NPROPP * NPREDD;      // keep mask  32*714
    float* outS = outK + (size_t)NB * NPROPP;              // scores     32*714

    float* ws = (float*)d_ws;
    float* A0 = ws;                   // [0, 688128)         dead after gemm1
    float* C1 = ws + 688128;          // [688128, 2064384)   dead after gemm2
    float* C2 = ws + 2064384;         // [2064384, 3784704)
    // reuse A0 region (dead by the time these are written):
    float* startv = ws;                                    // 32*720 floats
    float* endv   = ws + 23040;                            // 32*720 floats
    int*   order  = (int*)(ws + 46080);                    // 32*720 ints
    unsigned long long* sup = (unsigned long long*)(ws + 69120);  // 32*714*12 u64 = 2.09 MiB

    k_gather  <<<dim3(2688),        dim3(256), 0, stream>>>(feat, A0);
    k_gemm1   <<<dim3(16, 21),      dim3(256), 0, stream>>>(A0, Wconv, bconv, C1);
    k_gemm2   <<<dim3(20, 21),      dim3(256), 0, stream>>>(C1, Wcls, bcls, Wreg, breg, C2);
    k_assemble<<<dim3(MTOT),        dim3(256), 0, stream>>>(C2, AD, outP, outS, startv, endv);
    k_sort    <<<dim3(NB),          dim3(256), 0, stream>>>(outS, order);
    k_supmat  <<<dim3(12, 23, NB),  dim3(256), 0, stream>>>(outP, startv, endv, order, sup);
    k_scan    <<<dim3(NB),          dim3(64),  0, stream>>>(sup, order, outK);
}

// Round 3
// 363.999 us; speedup vs baseline: 1.4090x; 1.1797x over previous
//
#include <hip/hip_runtime.h>
#include <math.h>

#define NB     32
#define FH     11
#define FW     20
#define CIN    512
#define CMID   1024
#define NANG   17
#define NPREDD 77
#define NEDGE  42
#define NPROPP 714
#define NOFF   72
#define NCLS   34
#define NREGR  1241
#define N2PAD  1280
#define MTOT   1344      // NB * NEDGE
#define NSTRIPSF 71.0f

typedef unsigned long long u64;

// ---------------- gather edge pixels: A0[m][c], m = b*42+e ----------------
__global__ __launch_bounds__(256) void k_gather(const float* __restrict__ feat,
                                                float* __restrict__ A0)
{
    int idx = blockIdx.x * 256 + threadIdx.x;    // exactly MTOT*CIN = 688128
    int m = idx >> 9, c = idx & 511;
    int b = m / NEDGE, e = m - b * NEDGE;
    int h, w;
    if (e < FH)          { h = e;      w = 0;      }
    else if (e < 2 * FH) { h = e - FH; w = FW - 1; }
    else                 { h = FH - 1; w = e - 2 * FH; }
    A0[idx] = feat[((size_t)(b * CIN + c) * FH + h) * FW + w];
}

// ---------------- GEMM1: C1[1344][1024] = A0[1344][512] * Wconv[1024][512]^T + b ----
__global__ __launch_bounds__(256) void k_gemm1(const float* __restrict__ A,
                                               const float* __restrict__ W,
                                               const float* __restrict__ bias,
                                               float* __restrict__ C)
{
    __shared__ __align__(16) float As[16][68];
    __shared__ __align__(16) float Bs[16][68];
    const int K = CIN;
    int tid = threadIdx.x;
    int m0 = blockIdx.y * 64, n0 = blockIdx.x * 64;
    int tn = tid & 15, tm = tid >> 4;
    int lr = tid >> 2, lc = (tid & 3) << 2;
    const float* Ap = A + (size_t)(m0 + lr) * K + lc;
    const float* Wp = W + (size_t)(n0 + lr) * K + lc;
    float acc[4][4];
#pragma unroll
    for (int i = 0; i < 4; ++i)
#pragma unroll
        for (int j = 0; j < 4; ++j) acc[i][j] = 0.f;

    for (int k0 = 0; k0 < K; k0 += 16) {
        float4 av = *(const float4*)(Ap + k0);
        float4 wv = *(const float4*)(Wp + k0);
        As[lc + 0][lr] = av.x; As[lc + 1][lr] = av.y; As[lc + 2][lr] = av.z; As[lc + 3][lr] = av.w;
        Bs[lc + 0][lr] = wv.x; Bs[lc + 1][lr] = wv.y; Bs[lc + 2][lr] = wv.z; Bs[lc + 3][lr] = wv.w;
        __syncthreads();
#pragma unroll
        for (int kk = 0; kk < 16; ++kk) {
            float4 a = *(const float4*)&As[kk][tm << 2];
            float4 b = *(const float4*)&Bs[kk][tn << 2];
            float ar[4] = {a.x, a.y, a.z, a.w};
            float br[4] = {b.x, b.y, b.z, b.w};
#pragma unroll
            for (int i = 0; i < 4; ++i)
#pragma unroll
                for (int j = 0; j < 4; ++j)
                    acc[i][j] = fmaf(ar[i], br[j], acc[i][j]);
        }
        __syncthreads();
    }
    float bb[4];
#pragma unroll
    for (int j = 0; j < 4; ++j) bb[j] = bias[n0 + (tn << 2) + j];
#pragma unroll
    for (int i = 0; i < 4; ++i) {
        float4 o;
        o.x = acc[i][0] + bb[0];
        o.y = acc[i][1] + bb[1];
        o.z = acc[i][2] + bb[2];
        o.w = acc[i][3] + bb[3];
        *(float4*)(C + (size_t)(m0 + (tm << 2) + i) * CMID + n0 + (tn << 2)) = o;
    }
}

// ---------------- GEMM2: C2[1344][1280] = C1 * [Wcls;Wreg;0]^T + [bcls;breg;0] ----
__global__ __launch_bounds__(256) void k_gemm2(const float* __restrict__ A,
                                               const float* __restrict__ Wcls,
                                               const float* __restrict__ bcls,
                                               const float* __restrict__ Wreg,
                                               const float* __restrict__ breg,
                                               float* __restrict__ C)
{
    __shared__ __align__(16) float As[16][68];
    __shared__ __align__(16) float Bs[16][68];
    const int K = CMID;
    int tid = threadIdx.x;
    int m0 = blockIdx.y * 64, n0 = blockIdx.x * 64;
    int tn = tid & 15, tm = tid >> 4;
    int lr = tid >> 2, lc = (tid & 3) << 2;
    int nrow = n0 + lr;
    const float* Wp = Wcls;
    bool wvalid = true;
    if (nrow < NCLS)              Wp = Wcls + (size_t)nrow * K + lc;
    else if (nrow < NCLS + NREGR) Wp = Wreg + (size_t)(nrow - NCLS) * K + lc;
    else                          wvalid = false;
    const float* Ap = A + (size_t)(m0 + lr) * K + lc;
    float acc[4][4];
#pragma unroll
    for (int i = 0; i < 4; ++i)
#pragma unroll
        for (int j = 0; j < 4; ++j) acc[i][j] = 0.f;

    for (int k0 = 0; k0 < K; k0 += 16) {
        float4 av = *(const float4*)(Ap + k0);
        float4 wv = wvalid ? *(const float4*)(Wp + k0) : make_float4(0.f, 0.f, 0.f, 0.f);
        As[lc + 0][lr] = av.x; As[lc + 1][lr] = av.y; As[lc + 2][lr] = av.z; As[lc + 3][lr] = av.w;
        Bs[lc + 0][lr] = wv.x; Bs[lc + 1][lr] = wv.y; Bs[lc + 2][lr] = wv.z; Bs[lc + 3][lr] = wv.w;
        __syncthreads();
#pragma unroll
        for (int kk = 0; kk < 16; ++kk) {
            float4 a = *(const float4*)&As[kk][tm << 2];
            float4 b = *(const float4*)&Bs[kk][tn << 2];
            float ar[4] = {a.x, a.y, a.z, a.w};
            float br[4] = {b.x, b.y, b.z, b.w};
#pragma unroll
            for (int i = 0; i < 4; ++i)
#pragma unroll
                for (int j = 0; j < 4; ++j)
                    acc[i][j] = fmaf(ar[i], br[j], acc[i][j]);
        }
        __syncthreads();
    }
    float bb[4];
#pragma unroll
    for (int j = 0; j < 4; ++j) {
        int n = n0 + (tn << 2) + j;
        bb[j] = (n < NCLS) ? bcls[n] : ((n < NCLS + NREGR) ? breg[n - NCLS] : 0.f);
    }
#pragma unroll
    for (int i = 0; i < 4; ++i) {
        float4 o;
        o.x = acc[i][0] + bb[0];
        o.y = acc[i][1] + bb[1];
        o.z = acc[i][2] + bb[2];
        o.w = acc[i][3] + bb[3];
        *(float4*)(C + (size_t)(m0 + (tm << 2) + i) * N2PAD + n0 + (tn << 2)) = o;
    }
}

// ---------------- assemble proposals + scores + start/end ----------------
__global__ __launch_bounds__(256) void k_assemble(const float* __restrict__ C2,
                                                  const float* __restrict__ AD,
                                                  float* __restrict__ outP,
                                                  float* __restrict__ outS,
                                                  float* __restrict__ startv,
                                                  float* __restrict__ endv)
{
    int mb = blockIdx.x;                 // 0..1343
    int b = mb / NEDGE, e = mb - b * NEDGE;
    const float* c2 = C2 + (size_t)mb * N2PAD;
    int tid = threadIdx.x;
    for (int idx = tid; idx < NANG * NPREDD; idx += 256) {
        int a = idx / NPREDD, p = idx - a * NPREDD;
        int prop = e * NANG + a;
        float v;
        if (p < 2) v = c2[a * 2 + p];
        else {
            v = AD[prop * NPREDD + p];
            if (p >= 4) v += c2[NCLS + a * 73 + (p - 4)];
        }
        outP[((size_t)b * NPROPP + prop) * NPREDD + p] = v;
    }
    if (tid < NANG) {
        int a = tid, prop = e * NANG + a;
        float c0 = c2[2 * a], c1 = c2[2 * a + 1];
        float mx = fmaxf(c0, c1);
        float e0 = expf(c0 - mx), e1 = expf(c1 - mx);
        outS[b * NPROPP + prop] = e1 / (e0 + e1);
        float p2 = AD[prop * NPREDD + 2];
        float p4 = AD[prop * NPREDD + 4] + c2[NCLS + a * 73];
        float st = fminf(fmaxf(rintf(p2 * NSTRIPSF), 0.0f), NSTRIPSF);  // round half-to-even
        float en = fminf(fmaxf(st + p4 - 1.0f, 0.0f), NSTRIPSF);
        startv[b * 720 + prop] = st;
        endv[b * 720 + prop] = en;
    }
}

// ---------------- per-batch stable descending rank sort ----------------
__global__ __launch_bounds__(256) void k_sort(const float* __restrict__ scores,
                                              int* __restrict__ order)
{
    int b = blockIdx.x, tid = threadIdx.x;
    __shared__ float s[NPROPP];
    for (int i = tid; i < NPROPP; i += 256) s[i] = scores[b * NPROPP + i];
    __syncthreads();
    for (int i = tid; i < NPROPP; i += 256) {
        float si = s[i];
        int r = 0;
        for (int j = 0; j < NPROPP; ++j) {
            float sj = s[j];
            r += (sj > si) || (sj == si && j < i);
        }
        order[b * 720 + r] = i;
    }
}

// ---------------- suppression matrix in sorted order, bit-packed ----------------
// Bits are emitted ONLY for j > i (ballot predicate); below-diagonal j-tiles
// write literal zero words. This lets the scan OR whole words unmasked.
#define SUP_IT 32
#define SUP_JT 64
__global__ __launch_bounds__(256) void k_supmat(const float* __restrict__ outP,
                                                const float* __restrict__ startv,
                                                const float* __restrict__ endv,
                                                const int* __restrict__ order,
                                                u64* __restrict__ sup)
{
    int jt = blockIdx.x, it = blockIdx.y, b = blockIdx.z;
    int i0 = it * SUP_IT, j0 = jt * SUP_JT;
    int tid = threadIdx.x;
    if (j0 + SUP_JT - 1 < i0) {          // strictly below diagonal: all-zero words
        if (tid < SUP_IT) {
            int il = i0 + tid;
            if (il < NPROPP) sup[((size_t)b * NPROPP + il) * 12 + jt] = 0ull;
        }
        return;
    }
    __shared__ float XI[SUP_IT][73];
    __shared__ float XJ[SUP_JT][73];
    __shared__ float SI[SUP_IT], EI[SUP_IT], SJ[SUP_JT], EJ[SUP_JT];
    __shared__ int   OIJ[SUP_IT + SUP_JT];
    if (tid < SUP_IT + SUP_JT) {
        int pos = (tid < SUP_IT) ? (i0 + tid) : (j0 + (tid - SUP_IT));
        int o = (pos < NPROPP) ? order[b * 720 + pos] : -1;
        OIJ[tid] = o;
        float st = (o >= 0) ? startv[b * 720 + o] : 0.f;
        float en = (o >= 0) ? endv[b * 720 + o] : -2.f;   // cnt<=-1 -> never suppress
        if (tid < SUP_IT) { SI[tid] = st; EI[tid] = en; }
        else              { SJ[tid - SUP_IT] = st; EJ[tid - SUP_IT] = en; }
    }
    __syncthreads();
    for (int x = tid; x < (SUP_IT + SUP_JT) * NOFF; x += 256) {
        int r = x / NOFF, k = x - r * NOFF;
        int o = OIJ[r];
        float v = (o >= 0) ? outP[((size_t)b * NPROPP + o) * NPREDD + 5 + k] : 0.f;
        if (r < SUP_IT) XI[r][k] = v; else XJ[r - SUP_IT][k] = v;
    }
    __syncthreads();
    int lane = tid & 63, wv = tid >> 6;
    int j = j0 + lane;
    float sj = SJ[lane], ej = EJ[lane];
#pragma unroll 1
    for (int rep = 0; rep < 8; ++rep) {
        int iloc = wv * 8 + rep;
        int il = i0 + iloc;
        float si = SI[iloc], ei = EI[iloc];
        float s = fmaxf(si, sj), e = fminf(ei, ej);
        float cnt = e - s + 1.0f;
        bool sp = false;
        if (cnt > 0.f) {
            int ks = (int)s;            // s is integer-valued, >= 0
            int ke = (int)e;            // e >= 0 here; trunc == floor
            float sum = 0.f;
            for (int k = ks; k <= ke; ++k)     // typically 0..2 iterations
                sum += fabsf(XI[iloc][k] - XJ[lane][k]);
            sp = (sum / fmaxf(cnt, 1.0f)) < 15.0f;
        }
        bool valid = (il < NPROPP) && (j < NPROPP) && (j > il);
        u64 msk = __ballot(valid && sp);
        if (lane == 0 && il < NPROPP)
            sup[((size_t)b * NPROPP + il) * 12 + jt] = msk;
    }
}

// ---------------- sequential NMS scan (per batch, 1 wave) ----------------
// State held as a SHIFTED array S[t] = suppression word for chunk (c+t), so all
// indexing is static. Row words are cached per-lane (lane l holds sorted row
// c*64+l) and broadcast via v_readlane into SGPRs -> the hot loop is scalar:
// suppressed iters cost ~5 SALU ops, kept iters 24 readlane + 12 s_or_b64.
__global__ __launch_bounds__(64) void k_scan(const u64* __restrict__ sup,
                                             const int* __restrict__ order,
                                             float* __restrict__ keep_out)
{
    int b = blockIdx.x, lane = threadIdx.x;
    __shared__ float keepv[NPROPP];
    __shared__ int ord[NPROPP];
    for (int x = lane; x < NPROPP; x += 64) { keepv[x] = 0.f; ord[x] = order[b * 720 + x]; }
    __syncthreads();
    const u64* base = sup + (size_t)b * NPROPP * 12;

    u64 S[12];
#pragma unroll
    for (int t = 0; t < 12; ++t) S[t] = 0ull;

    u64 cur[12], nxt[12];
    {   // load chunk 0, shifted: cur[t] = word t of row `lane`
        int r = lane;
#pragma unroll
        for (int t = 0; t < 12; ++t)
            cur[t] = (r < NPROPP) ? base[(size_t)r * 12 + t] : 0ull;
    }

    for (int c = 0; c < 12; ++c) {
        // prefetch next chunk, shifted by (c+1)
        if (c < 11) {
            int r = (c + 1) * 64 + lane;
#pragma unroll
            for (int t = 0; t < 12; ++t) {
                int w = c + 1 + t;
                nxt[t] = (r < NPROPP && w < 12) ? base[(size_t)r * 12 + w] : 0ull;
            }
        }
        int imax = NPROPP - c * 64; if (imax > 64) imax = 64;
        u64 keepbits = 0ull;
        for (int ib = 0; ib < imax; ++ib) {
            bool keep = ((S[0] >> ib) & 1ull) == 0ull;   // uniform
            if (keep) {
                keepbits |= (1ull << ib);
#pragma unroll
                for (int t = 0; t < 12; ++t) {
                    unsigned rlo = (unsigned)__builtin_amdgcn_readlane((int)(unsigned)cur[t], ib);
                    unsigned rhi = (unsigned)__builtin_amdgcn_readlane((int)(cur[t] >> 32), ib);
                    S[t] |= ((u64)rhi << 32) | (u64)rlo;
                }
            }
        }
        if (lane < imax)
            keepv[ord[c * 64 + lane]] = ((keepbits >> lane) & 1ull) ? 1.f : 0.f;
        // shift state down one chunk
#pragma unroll
        for (int t = 0; t < 11; ++t) S[t] = S[t + 1];
        S[11] = 0ull;
#pragma unroll
        for (int t = 0; t < 12; ++t) cur[t] = nxt[t];
    }
    __syncthreads();
    for (int x = lane; x < NPROPP; x += 64) keep_out[b * NPROPP + x] = keepv[x];
}

extern "C" void kernel_launch(void* const* d_in, const int* in_sizes, int n_in,
                              void* d_out, int out_size, void* d_ws, size_t ws_size,
                              hipStream_t stream)
{
    const float* feat  = (const float*)d_in[0];
    const float* Wconv = (const float*)d_in[1];
    const float* bconv = (const float*)d_in[2];
    const float* Wcls  = (const float*)d_in[3];
    const float* bcls  = (const float*)d_in[4];
    const float* Wreg  = (const float*)d_in[5];
    const float* breg  = (const float*)d_in[6];
    const float* AD    = (const float*)d_in[8];   // anchors_anchor_dim (714,77)

    float* out  = (float*)d_out;
    float* outP = out;                                     // proposals 32*714*77
    float* outK = out + (size_t)NB * NPROPP * NPREDD;      // keep mask  32*714
    float* outS = outK + (size_t)NB * NPROPP;              // scores     32*714

    float* ws = (float*)d_ws;
    float* A0 = ws;                   // [0, 688128)         dead after gemm1
    float* C1 = ws + 688128;          // [688128, 2064384)   dead after gemm2
    float* C2 = ws + 2064384;         // [2064384, 3784704)
    // reuse A0 region (dead by the time these are written):
    float* startv = ws;                                    // 32*720 floats
    float* endv   = ws + 23040;                            // 32*720 floats
    int*   order  = (int*)(ws + 46080);                    // 32*720 ints
    u64*   sup    = (u64*)(ws + 69120);                    // 32*714*12 u64 = 2.09 MiB

    k_gather  <<<dim3(2688),        dim3(256), 0, stream>>>(feat, A0);
    k_gemm1   <<<dim3(16, 21),      dim3(256), 0, stream>>>(A0, Wconv, bconv, C1);
    k_gemm2   <<<dim3(20, 21),      dim3(256), 0, stream>>>(C1, Wcls, bcls, Wreg, breg, C2);
    k_assemble<<<dim3(MTOT),        dim3(256), 0, stream>>>(C2, AD, outP, outS, startv, endv);
    k_sort    <<<dim3(NB),          dim3(256), 0, stream>>>(outS, order);
    k_supmat  <<<dim3(12, 23, NB),  dim3(256), 0, stream>>>(outP, startv, endv, order, sup);
    k_scan    <<<dim3(NB),          dim3(64),  0, stream>>>(sup, order, outK);
}